// Round 9
// baseline (535.335 us; speedup 1.0000x reference)
//
#include <hip/hip_runtime.h>
#include <hip/hip_bf16.h>

#define B_ 4
#define H_ 16
#define L_ 2048
#define D_ 128
#define BH_ 64

typedef __attribute__((ext_vector_type(8))) _Float16 f16x8;
typedef __attribute__((ext_vector_type(4))) float f32x4;
typedef __attribute__((ext_vector_type(16))) float f32x16;
typedef __attribute__((ext_vector_type(2))) unsigned u32x2;

#define L2E 1.44269504088896f

// gm = L2E*gelu(v) + negm. erf via A&S 7.1.27 (|eps|<=5e-4, gelu err <=7e-4):
// erf(x) = 1 - (1 + a1 x + a2 x^2 + a3 x^3 + a4 x^4)^-4. No exp2 needed --
// one rcp is the only transcendental (saves a 4-8cy exp2 + a live temp vs R8).
__device__ __forceinline__ float gelu_m(float v, float negm) {
  float x  = __builtin_fabsf(v) * 0.70710678118f;
  float s  = __builtin_fmaf(x,
               __builtin_fmaf(x,
                 __builtin_fmaf(x,
                   __builtin_fmaf(x, 0.078108f, 0.000972f),
                 0.230389f),
               0.278393f),
             1.0f);
  float s2 = s * s;
  float s4 = s2 * s2;
  float erfa = 1.0f - __builtin_amdgcn_rcpf(s4);   // erf(|v|/sqrt2) in [0,1)
  float erfv = copysignf(erfa, v);
  float hv   = 0.72134752f * v;                    // 0.5*L2E*v
  return __builtin_fmaf(hv, erfv, hv + negm);      // hv*(1+erfv) + negm
}

__device__ __forceinline__ void gl2lds16(const void* g, void* l) {
  __builtin_amdgcn_global_load_lds(
      (const __attribute__((address_space(1))) void*)g,
      (__attribute__((address_space(3))) void*)l, 16, 0, 0);
}

__device__ __forceinline__ unsigned pkrtz(float a, float b) {
  auto t = __builtin_amdgcn_cvt_pkrtz(a, b);   // __fp16 ext_vector(2)
  return __builtin_bit_cast(unsigned, t);
}

// ---------------------------------------------------------------------------
// Kernel 0: one-time W1,W2 f32 -> f16 (scratch in d_out head; attn overwrites).
// ---------------------------------------------------------------------------
__global__ __launch_bounds__(256) void wcvt_kernel(
    const float* __restrict__ W1, const float* __restrict__ W2,
    _Float16* __restrict__ Wh1, _Float16* __restrict__ Wh2)
{
  int i = blockIdx.x * 256 + threadIdx.x;
  Wh1[i] = (_Float16)W1[i];
  Wh2[i] = (_Float16)W2[i];
}

// ---------------------------------------------------------------------------
// Kernel 1: q/k projections (f16 MFMA, f32 accum, +bias) and x -> V^T (f16).
// ---------------------------------------------------------------------------
__global__ __launch_bounds__(256) void proj_tr_kernel(
    const float* __restrict__ x,
    const _Float16* __restrict__ Wh1, const float* __restrict__ b1,
    const _Float16* __restrict__ Wh2, const float* __restrict__ b2,
    _Float16* __restrict__ Qb, _Float16* __restrict__ Kb,
    _Float16* __restrict__ VT)
{
  const int tid  = threadIdx.x;
  const int wave = tid >> 6;
  const int lane = tid & 63;
  const int lhi  = lane >> 4;
  const int llo  = lane & 15;
  const int r0   = blockIdx.x * 64;
  const int wr0  = r0 + wave * 16;

  f16x8 a[4];
#pragma unroll
  for (int ks = 0; ks < 4; ++ks) {
    const float* p = x + (size_t)(wr0 + llo) * D_ + lhi * 8 + ks * 32;
    f16x8 t;
#pragma unroll
    for (int e = 0; e < 8; ++e) t[e] = (_Float16)p[e];
    a[ks] = t;
  }

  f32x4 accq[8], acck[8];
#pragma unroll
  for (int n = 0; n < 8; ++n) {
    accq[n] = (f32x4){0.f, 0.f, 0.f, 0.f};
    acck[n] = (f32x4){0.f, 0.f, 0.f, 0.f};
  }

#pragma unroll
  for (int n = 0; n < 8; ++n) {
    const int e = n * 16 + llo;
#pragma unroll
    for (int ks = 0; ks < 4; ++ks) {
      f16x8 w1f = *(const f16x8*)(Wh1 + (size_t)e * D_ + lhi * 8 + ks * 32);
      f16x8 w2f = *(const f16x8*)(Wh2 + (size_t)e * D_ + lhi * 8 + ks * 32);
      accq[n] = __builtin_amdgcn_mfma_f32_16x16x32_f16(a[ks], w1f, accq[n], 0, 0, 0);
      acck[n] = __builtin_amdgcn_mfma_f32_16x16x32_f16(a[ks], w2f, acck[n], 0, 0, 0);
    }
  }

#pragma unroll
  for (int n = 0; n < 8; ++n) {
    const int e = n * 16 + llo;
    const float bias1 = b1[e];
    const float bias2 = b2[e];
#pragma unroll
    for (int r = 0; r < 4; ++r) {
      const size_t row = (size_t)wr0 + lhi * 4 + r;
      Qb[row * D_ + e] = (_Float16)(accq[n][r] + bias1);
      Kb[row * D_ + e] = (_Float16)(acck[n][r] + bias2);
    }
  }

  const int bh = r0 / L_;
  const int l0 = r0 % L_;
  const int d  = tid & 127;
  const int rh = tid >> 7;
  _Float16* dst = VT + (size_t)bh * D_ * L_ + (size_t)d * L_ + l0 + rh * 32;
#pragma unroll
  for (int j = 0; j < 4; ++j) {
    f16x8 t;
#pragma unroll
    for (int e = 0; e < 8; ++e)
      t[e] = (_Float16)x[(size_t)(r0 + rh * 32 + j * 8 + e) * D_ + d];
    *(f16x8*)(dst + j * 8) = t;
  }
}

// ---------------------------------------------------------------------------
// Kernel 2: fused gelu(QK^T)->softmax->@V flash attention, 32x32x16 MFMA.
// OCCUPANCY BUILD: 4 waves x 32 q = 128 q/block, 1024 blocks.
// K tile 32x128 staged per iter (2x8KB dbuf); V tile 128x64 staged every
// OTHER iter (2x16KB dbuf) -> LDS 48KB -> 3 blocks/CU if regs <= 170/wave.
// gelu via rational erf (no exp2), T12 in-reg P->A-frag, defer-max.
// ---------------------------------------------------------------------------
__global__ __launch_bounds__(256) void attn_kernel(
    const _Float16* __restrict__ Qb, const _Float16* __restrict__ Kb,
    const _Float16* __restrict__ VT, float* __restrict__ out)
{
  __shared__ _Float16 Ks[2][32 * 128];   // 2 x 8KB
  __shared__ _Float16 Vs[2][128 * 64];   // 2 x 16KB

  const int tid  = threadIdx.x;
  const int wave = tid >> 6;      // 0..3
  const int lane = tid & 63;
  const int l5   = lane & 31;
  const int hi   = lane >> 5;

  // XCD swizzle: 1024 blocks, 8 XCDs -> 8 whole heads per XCD (1024%8==0).
  const int bid = blockIdx.x;
  const int blk = (bid & 7) * 128 + (bid >> 3);
  const int bh  = blk >> 4;            // 16 q-blocks (128 rows) per head
  const int q0  = (blk & 15) * 128;
  const int b   = bh >> 4;
  const int h   = bh & 15;
  const int wq0 = q0 + wave * 32;

  const char* KheadB = (const char*)(Kb + (size_t)bh * L_ * D_);
  const char* VheadB = (const char*)(VT + (size_t)bh * D_ * L_);

  // ---- staging constants ----
  // K tile 8KB = 2 calls x 4KB (256 thr x 16B). call c: row r=c*16+(tid>>4).
  int kdst[2], ksrc[2];
#pragma unroll
  for (int c = 0; c < 2; ++c) {
    kdst[c] = c * 4096 + wave * 1024;                  // wave-uniform dest
    const int r  = c * 16 + (tid >> 4);
    const int h0 = (tid & 15) * 8;                     // col halves
    ksrc[c] = r * 256 + 2 * (h0 ^ ((r & 7) << 3));     // pre-swizzled source
  }
  // V tile 16KB = 4 calls x 4KB. call c: d = c*32+(tid>>3), 8 thr x 16B per row.
  int vdst[4], vsrc[4];
#pragma unroll
  for (int c = 0; c < 4; ++c) {
    vdst[c] = c * 4096 + wave * 1024;
    const int d  = c * 32 + (tid >> 3);
    const int h0 = (tid & 7) * 8;
    vsrc[c] = d * 4096 + 2 * (h0 ^ ((d & 7) << 3));
  }
  const int kvswz = (l5 & 7) << 3;                     // read-side XOR (halves)

  // Q fragments (B-operand of swapped QK^T): j = l5 = q-row, k = s*16+hi*8+e
  f16x8 qf[8];
#pragma unroll
  for (int s = 0; s < 8; ++s)
    qf[s] = *(const f16x8*)(Qb + ((size_t)bh * L_ + wq0 + l5) * D_ + s * 16 + hi * 8);

  f32x16 accO[4];
#pragma unroll
  for (int n = 0; n < 4; ++n)
#pragma unroll
    for (int r = 0; r < 16; ++r) accO[n][r] = 0.f;
  float negm = 64.f;   // -m in exp2 units; m init -64
  float l = 0.f;

  // ---- prologue: stage K[0], V[0] ----
#pragma unroll
  for (int c = 0; c < 2; ++c)
    gl2lds16(KheadB + ksrc[c], (char*)&Ks[0][0] + kdst[c]);
#pragma unroll
  for (int c = 0; c < 4; ++c)
    gl2lds16(VheadB + vsrc[c], (char*)&Vs[0][0] + vdst[c]);
  __syncthreads();

  for (int t = 0; t < L_ / 32; ++t) {        // 64 iters, 32 k each
    const int kcur = t & 1;
    const int vcur = (t >> 1) & 1;
    // ---- prefetch: K every iter; V every other iter (2 tiles ahead) ----
    if (t + 1 < L_ / 32) {
      const char* kt_ = KheadB + (size_t)(t + 1) * 8192;
#pragma unroll
      for (int c = 0; c < 2; ++c)
        gl2lds16(kt_ + ksrc[c], (char*)&Ks[kcur ^ 1][0] + kdst[c]);
    }
    if ((t & 1) == 0 && (t >> 1) + 1 < L_ / 64) {
      const char* vt_ = VheadB + (size_t)((t >> 1) + 1) * 128;
#pragma unroll
      for (int c = 0; c < 4; ++c)
        gl2lds16(vt_ + vsrc[c], (char*)&Vs[vcur ^ 1][0] + vdst[c]);
    }
    const _Float16* Kcur = &Ks[kcur][0];
    const _Float16* Vcur = &Vs[vcur][0];
    const int vkbase = (t & 1) * 32;         // which half of the V tile

    // ---- S^T = K Q^T : lane holds q=l5, k-rows (r&3)+8*(r>>2)+4*hi ----
    f32x16 sT;
#pragma unroll
    for (int r = 0; r < 16; ++r) sT[r] = 0.f;
    __builtin_amdgcn_s_setprio(1);
#pragma unroll
    for (int s = 0; s < 8; ++s) {
      f16x8 kf = *(const f16x8*)(Kcur + l5 * 128 + ((s * 16 + hi * 8) ^ kvswz));
      sT = __builtin_amdgcn_mfma_f32_32x32x16_f16(kf, qf[s], sT, 0, 0, 0);
    }
    __builtin_amdgcn_s_setprio(0);

    // ---- GELU (rational erf, no exp2) with -m folded in ----
    float gm[16];
#pragma unroll
    for (int r = 0; r < 16; ++r) gm[r] = gelu_m(sT[r], negm);

    // ---- subtile max + partner half ----
    float tm = fmaxf(fmaxf(gm[0], gm[1]), gm[2]);
    tm = fmaxf(fmaxf(tm, gm[3]),  gm[4]);
    tm = fmaxf(fmaxf(tm, gm[5]),  gm[6]);
    tm = fmaxf(fmaxf(tm, gm[7]),  gm[8]);
    tm = fmaxf(fmaxf(tm, gm[9]),  gm[10]);
    tm = fmaxf(fmaxf(tm, gm[11]), gm[12]);
    tm = fmaxf(fmaxf(tm, gm[13]), gm[14]);
    tm = fmaxf(tm, gm[15]);
    tm = fmaxf(tm, __shfl_xor(tm, 32));

    // ---- online softmax with defer-max (THR = 8 nats = 11.54 bits) ----
    float p[16];
    float ts;
    if (__all(tm <= 11.5415603f)) {
#pragma unroll
      for (int r = 0; r < 16; ++r) p[r] = __builtin_amdgcn_exp2f(gm[r]);
      float a0 = p[0]+p[1],   a1 = p[2]+p[3],   a2 = p[4]+p[5],   a3 = p[6]+p[7];
      float a4 = p[8]+p[9],   a5 = p[10]+p[11], a6 = p[12]+p[13], a7 = p[14]+p[15];
      ts = ((a0+a1)+(a2+a3)) + ((a4+a5)+(a6+a7));
      ts += __shfl_xor(ts, 32);
      l += ts;
    } else {
      float dm = fmaxf(tm, 0.f);
      negm -= dm;
      float sc = __builtin_amdgcn_exp2f(-dm);
#pragma unroll
      for (int r = 0; r < 16; ++r) p[r] = __builtin_amdgcn_exp2f(gm[r] - dm);
      float a0 = p[0]+p[1],   a1 = p[2]+p[3],   a2 = p[4]+p[5],   a3 = p[6]+p[7];
      float a4 = p[8]+p[9],   a5 = p[10]+p[11], a6 = p[12]+p[13], a7 = p[14]+p[15];
      ts = ((a0+a1)+(a2+a3)) + ((a4+a5)+(a6+a7));
      ts += __shfl_xor(ts, 32);
      l = __builtin_fmaf(l, sc, ts);
      float scr[16];
#pragma unroll
      for (int r = 0; r < 16; ++r)
        scr[r] = __shfl(sc, (r & 3) + 8 * (r >> 2) + 4 * hi);
#pragma unroll
      for (int n = 0; n < 4; ++n)
#pragma unroll
        for (int r = 0; r < 16; ++r) accO[n][r] *= scr[r];
    }

    // ---- P -> PV A-fragments in-register (T12) ----
    unsigned pk01 = pkrtz(p[0], p[1]),   pk23 = pkrtz(p[2], p[3]);
    unsigned pk45 = pkrtz(p[4], p[5]),   pk67 = pkrtz(p[6], p[7]);
    unsigned pk89 = pkrtz(p[8], p[9]),   pkAB = pkrtz(p[10], p[11]);
    unsigned pkCD = pkrtz(p[12], p[13]), pkEF = pkrtz(p[14], p[15]);
    u32x2 r0 = __builtin_amdgcn_permlane32_swap(pk01, pk45, false, false);
    u32x2 r1 = __builtin_amdgcn_permlane32_swap(pk23, pk67, false, false);
    u32x2 r2 = __builtin_amdgcn_permlane32_swap(pk89, pkCD, false, false);
    u32x2 r3 = __builtin_amdgcn_permlane32_swap(pkAB, pkEF, false, false);
    union { unsigned u[4]; f16x8 v; } A0c, A1c;
    A0c.u[0] = r0[0]; A0c.u[1] = r1[0]; A0c.u[2] = r0[1]; A0c.u[3] = r1[1];
    A1c.u[0] = r2[0]; A1c.u[1] = r3[0]; A1c.u[2] = r2[1]; A1c.u[3] = r3[1];

    // ---- O += P @ V (V rows 64 halves; half selected by vkbase) ----
    __builtin_amdgcn_s_setprio(1);
#pragma unroll
    for (int n = 0; n < 4; ++n) {
      f16x8 vf0 = *(const f16x8*)(Vcur + (n * 32 + l5) * 64 +
                                  ((vkbase + hi * 8) ^ kvswz));
      accO[n] = __builtin_amdgcn_mfma_f32_32x32x16_f16(A0c.v, vf0, accO[n], 0, 0, 0);
      f16x8 vf1 = *(const f16x8*)(Vcur + (n * 32 + l5) * 64 +
                                  ((vkbase + 16 + hi * 8) ^ kvswz));
      accO[n] = __builtin_amdgcn_mfma_f32_32x32x16_f16(A1c.v, vf1, accO[n], 0, 0, 0);
    }
    __builtin_amdgcn_s_setprio(0);

    __syncthreads();   // all waves done with cur buffers; prefetches drained
  }

  // ---- epilogue: O[q][d] / l[q]; q = (r&3)+8*(r>>2)+4*hi, d = n*32+l5 ----
  float linv = __builtin_amdgcn_rcpf(l);
  float lb[16];
#pragma unroll
  for (int r = 0; r < 16; ++r)
    lb[r] = __shfl(linv, (r & 3) + 8 * (r >> 2) + 4 * hi);
#pragma unroll
  for (int n = 0; n < 4; ++n)
#pragma unroll
    for (int r = 0; r < 16; ++r) {
      const int i = wq0 + (r & 3) + 8 * (r >> 2) + 4 * hi;
      out[((size_t)(b * L_ + i) * H_ + h) * D_ + n * 32 + l5] = accO[n][r] * lb[r];
    }
}

extern "C" void kernel_launch(void* const* d_in, const int* in_sizes, int n_in,
                              void* d_out, int out_size, void* d_ws, size_t ws_size,
                              hipStream_t stream) {
  const float* x  = (const float*)d_in[0];
  const float* W1 = (const float*)d_in[1];
  const float* b1 = (const float*)d_in[2];
  const float* W2 = (const float*)d_in[3];
  const float* b2 = (const float*)d_in[4];
  float* out = (float*)d_out;

  const size_t N = (size_t)BH_ * L_ * D_;
  _Float16* Qb = (_Float16*)d_ws;
  _Float16* Kb = Qb + N;
  _Float16* VT = Kb + N;

  _Float16* Wh1 = (_Float16*)d_out;          // scratch; attn overwrites out
  _Float16* Wh2 = Wh1 + D_ * D_;

  wcvt_kernel<<<64, 256, 0, stream>>>(W1, W2, Wh1, Wh2);
  proj_tr_kernel<<<(BH_ * L_) / 64, 256, 0, stream>>>(x, Wh1, b1, Wh2, b2, Qb, Kb, VT);
  attn_kernel<<<BH_ * (L_ / 128), 256, 0, stream>>>(Qb, Kb, VT, out);
}

// Round 11
// 370.135 us; speedup vs baseline: 1.4463x; 1.4463x over previous
//
#include <hip/hip_runtime.h>
#include <hip/hip_bf16.h>

#define B_ 4
#define H_ 16
#define L_ 2048
#define D_ 128
#define BH_ 64

typedef __attribute__((ext_vector_type(8))) _Float16 f16x8;
typedef __attribute__((ext_vector_type(4))) float f32x4;
typedef __attribute__((ext_vector_type(16))) float f32x16;
typedef __attribute__((ext_vector_type(2))) unsigned u32x2;

#define L2E 1.44269504088896f

// gm = L2E*gelu(v) + negm. erf via A&S 7.1.27 (|eps|<=5e-4): one rcp, no exp2.
// Verified absmax-neutral vs exact erf in R9 (error budget is the f16 P path).
__device__ __forceinline__ float gelu_m(float v, float negm) {
  float x  = __builtin_fabsf(v) * 0.70710678118f;
  float s  = __builtin_fmaf(x,
               __builtin_fmaf(x,
                 __builtin_fmaf(x,
                   __builtin_fmaf(x, 0.078108f, 0.000972f),
                 0.230389f),
               0.278393f),
             1.0f);
  float s2 = s * s;
  float s4 = s2 * s2;
  float erfa = 1.0f - __builtin_amdgcn_rcpf(s4);   // erf(|v|/sqrt2) in [0,1)
  float erfv = copysignf(erfa, v);
  float hv   = 0.72134752f * v;                    // 0.5*L2E*v
  return __builtin_fmaf(hv, erfv, hv + negm);      // hv*(1+erfv) + negm
}

__device__ __forceinline__ void gl2lds16(const void* g, void* l) {
  __builtin_amdgcn_global_load_lds(
      (const __attribute__((address_space(1))) void*)g,
      (__attribute__((address_space(3))) void*)l, 16, 0, 0);
}

__device__ __forceinline__ unsigned pkrtz(float a, float b) {
  auto t = __builtin_amdgcn_cvt_pkrtz(a, b);   // __fp16 ext_vector(2)
  return __builtin_bit_cast(unsigned, t);
}

// ---------------------------------------------------------------------------
// Kernel 0: one-time W1,W2 f32 -> f16 (scratch in d_out head; attn overwrites).
// ---------------------------------------------------------------------------
__global__ __launch_bounds__(256) void wcvt_kernel(
    const float* __restrict__ W1, const float* __restrict__ W2,
    _Float16* __restrict__ Wh1, _Float16* __restrict__ Wh2)
{
  int i = blockIdx.x * 256 + threadIdx.x;
  Wh1[i] = (_Float16)W1[i];
  Wh2[i] = (_Float16)W2[i];
}

// ---------------------------------------------------------------------------
// Kernel 1: q/k projections (f16 MFMA, f32 accum, +bias) and x -> V^T (f16).
// ---------------------------------------------------------------------------
__global__ __launch_bounds__(256) void proj_tr_kernel(
    const float* __restrict__ x,
    const _Float16* __restrict__ Wh1, const float* __restrict__ b1,
    const _Float16* __restrict__ Wh2, const float* __restrict__ b2,
    _Float16* __restrict__ Qb, _Float16* __restrict__ Kb,
    _Float16* __restrict__ VT)
{
  const int tid  = threadIdx.x;
  const int wave = tid >> 6;
  const int lane = tid & 63;
  const int lhi  = lane >> 4;
  const int llo  = lane & 15;
  const int r0   = blockIdx.x * 64;
  const int wr0  = r0 + wave * 16;

  f16x8 a[4];
#pragma unroll
  for (int ks = 0; ks < 4; ++ks) {
    const float* p = x + (size_t)(wr0 + llo) * D_ + lhi * 8 + ks * 32;
    f16x8 t;
#pragma unroll
    for (int e = 0; e < 8; ++e) t[e] = (_Float16)p[e];
    a[ks] = t;
  }

  f32x4 accq[8], acck[8];
#pragma unroll
  for (int n = 0; n < 8; ++n) {
    accq[n] = (f32x4){0.f, 0.f, 0.f, 0.f};
    acck[n] = (f32x4){0.f, 0.f, 0.f, 0.f};
  }

#pragma unroll
  for (int n = 0; n < 8; ++n) {
    const int e = n * 16 + llo;
#pragma unroll
    for (int ks = 0; ks < 4; ++ks) {
      f16x8 w1f = *(const f16x8*)(Wh1 + (size_t)e * D_ + lhi * 8 + ks * 32);
      f16x8 w2f = *(const f16x8*)(Wh2 + (size_t)e * D_ + lhi * 8 + ks * 32);
      accq[n] = __builtin_amdgcn_mfma_f32_16x16x32_f16(a[ks], w1f, accq[n], 0, 0, 0);
      acck[n] = __builtin_amdgcn_mfma_f32_16x16x32_f16(a[ks], w2f, acck[n], 0, 0, 0);
    }
  }

#pragma unroll
  for (int n = 0; n < 8; ++n) {
    const int e = n * 16 + llo;
    const float bias1 = b1[e];
    const float bias2 = b2[e];
#pragma unroll
    for (int r = 0; r < 4; ++r) {
      const size_t row = (size_t)wr0 + lhi * 4 + r;
      Qb[row * D_ + e] = (_Float16)(accq[n][r] + bias1);
      Kb[row * D_ + e] = (_Float16)(acck[n][r] + bias2);
    }
  }

  const int bh = r0 / L_;
  const int l0 = r0 % L_;
  const int d  = tid & 127;
  const int rh = tid >> 7;
  _Float16* dst = VT + (size_t)bh * D_ * L_ + (size_t)d * L_ + l0 + rh * 32;
#pragma unroll
  for (int j = 0; j < 4; ++j) {
    f16x8 t;
#pragma unroll
    for (int e = 0; e < 8; ++e)
      t[e] = (_Float16)x[(size_t)(r0 + rh * 32 + j * 8 + e) * D_ + d];
    *(f16x8*)(dst + j * 8) = t;
  }
}

// ---------------------------------------------------------------------------
// Kernel 2: fused gelu(QK^T)->softmax->@V flash attention, 32x32x16 MFMA.
// R8 structure (best measured): 8 waves x 32 q = 256 q/block, K/V 64-k tiles
// LDS dbuf via gl2lds. Deltas vs R8: rational gelu (no exp2), split QK
// accumulator chains. Cross-half reductions stay on __shfl_xor (R10 lesson:
// permlane32_swap with ALIASED operands is destructive-in-place -> garbage).
// ---------------------------------------------------------------------------
__global__ __launch_bounds__(512) void attn_kernel(
    const _Float16* __restrict__ Qb, const _Float16* __restrict__ Kb,
    const _Float16* __restrict__ VT, float* __restrict__ out)
{
  __shared__ _Float16 Ks[2][64 * 128];   // 2 x 16KB
  __shared__ _Float16 Vs[2][128 * 64];   // 2 x 16KB

  const int tid  = threadIdx.x;
  const int wave = tid >> 6;      // 0..7
  const int lane = tid & 63;
  const int l5   = lane & 31;
  const int hi   = lane >> 5;

  // XCD-aware swizzle: 512 blocks, 8 XCDs -> 8 whole heads per XCD.
  const int bid = blockIdx.x;
  const int blk = (bid & 7) * 64 + (bid >> 3);
  const int bh  = blk >> 3;            // 8 q-blocks (256 rows) per head
  const int q0  = (blk & 7) * 256;
  const int b   = bh >> 4;
  const int h   = bh & 15;
  const int wq0 = q0 + wave * 32;

  const char* KheadB = (const char*)(Kb + (size_t)bh * L_ * D_);
  const char* VheadB = (const char*)(VT + (size_t)bh * D_ * L_);

  // ---- staging constants (16KB tile = 8 waves x 2 calls x 1KB each) ----
  int klds[2], ksrc[2], vlds[2], vsrc[2];
#pragma unroll
  for (int c = 0; c < 2; ++c) {
    const int wc = wave * 2 + c;
    klds[c] = wc * 1024;                               // wave-uniform LDS dest
    {
      const int l  = wc * 4 + (lane >> 4);             // K-tile row
      const int c0 = (lane & 15) * 8;                  // col halves
      ksrc[c] = l * 256 + 2 * (c0 ^ ((l & 7) << 3));   // pre-swizzled source
    }
    vlds[c] = wc * 1024;
    {
      const int d  = wc * 8 + (lane >> 3);             // V-tile row (d)
      const int c0 = (lane & 7) * 8;
      vsrc[c] = d * 4096 + 2 * (c0 ^ ((d & 7) << 3));
    }
  }
  const int kvswz = (l5 & 7) << 3;                     // read-side XOR (halves)

  // Q fragments (B-operand of swapped QK^T): j = l5 = q-row, k = s*16+hi*8+e
  f16x8 qf[8];
#pragma unroll
  for (int s = 0; s < 8; ++s)
    qf[s] = *(const f16x8*)(Qb + ((size_t)bh * L_ + wq0 + l5) * D_ + s * 16 + hi * 8);

  f32x16 accO[4];
#pragma unroll
  for (int n = 0; n < 4; ++n)
#pragma unroll
    for (int r = 0; r < 16; ++r) accO[n][r] = 0.f;
  float negm = 64.f;   // -m in exp2 units; m init -64
  float l = 0.f;

  // ---- prologue: stage tile 0 ----
#pragma unroll
  for (int c = 0; c < 2; ++c) {
    gl2lds16(KheadB + ksrc[c], (char*)&Ks[0][0] + klds[c]);
    gl2lds16(VheadB + vsrc[c], (char*)&Vs[0][0] + vlds[c]);
  }
  __syncthreads();

  int cur = 0;
  for (int t = 0; t < L_ / 64; ++t) {
    // ---- prefetch next K/V tile (in flight across the tile body) ----
    if (t + 1 < L_ / 64) {
      const char* kt_ = KheadB + (size_t)(t + 1) * 64 * 256;
      const char* vt_ = VheadB + (size_t)(t + 1) * 128;
#pragma unroll
      for (int c = 0; c < 2; ++c) {
        gl2lds16(kt_ + ksrc[c], (char*)&Ks[cur ^ 1][0] + klds[c]);
        gl2lds16(vt_ + vsrc[c], (char*)&Vs[cur ^ 1][0] + vlds[c]);
      }
    }
    const _Float16* Kcur = &Ks[cur][0];
    const _Float16* Vcur = &Vs[cur][0];

#pragma unroll
    for (int kb = 0; kb < 2; ++kb) {
      // ---- S^T = K Q^T, two independent accumulator chains (4-deep each) --
      f32x16 sTa, sTb;
#pragma unroll
      for (int r = 0; r < 16; ++r) { sTa[r] = 0.f; sTb[r] = 0.f; }
      __builtin_amdgcn_s_setprio(1);
#pragma unroll
      for (int s = 0; s < 4; ++s) {
        f16x8 kfa = *(const f16x8*)(Kcur + (kb * 32 + l5) * 128 +
                                    ((s * 16 + hi * 8) ^ kvswz));
        sTa = __builtin_amdgcn_mfma_f32_32x32x16_f16(kfa, qf[s], sTa, 0, 0, 0);
        f16x8 kfb = *(const f16x8*)(Kcur + (kb * 32 + l5) * 128 +
                                    (((s + 4) * 16 + hi * 8) ^ kvswz));
        sTb = __builtin_amdgcn_mfma_f32_32x32x16_f16(kfb, qf[s + 4], sTb, 0, 0, 0);
      }
      __builtin_amdgcn_s_setprio(0);

      // ---- GELU (rational erf) with -m folded in; sT = sTa + sTb ----
      float gm[16];
#pragma unroll
      for (int r = 0; r < 16; ++r) gm[r] = gelu_m(sTa[r] + sTb[r], negm);

      // ---- subtile max (max3-fused chain) + cross-half shuffle ----
      float tm = fmaxf(fmaxf(gm[0], gm[1]), gm[2]);
      tm = fmaxf(fmaxf(tm, gm[3]),  gm[4]);
      tm = fmaxf(fmaxf(tm, gm[5]),  gm[6]);
      tm = fmaxf(fmaxf(tm, gm[7]),  gm[8]);
      tm = fmaxf(fmaxf(tm, gm[9]),  gm[10]);
      tm = fmaxf(fmaxf(tm, gm[11]), gm[12]);
      tm = fmaxf(fmaxf(tm, gm[13]), gm[14]);
      tm = fmaxf(tm, gm[15]);
      tm = fmaxf(tm, __shfl_xor(tm, 32));

      // ---- online softmax with defer-max (THR = 8 nats = 11.54 bits) ----
      float p[16];
      float ts;
      if (__all(tm <= 11.5415603f)) {
#pragma unroll
        for (int r = 0; r < 16; ++r) p[r] = __builtin_amdgcn_exp2f(gm[r]);
        float a0 = p[0]+p[1],   a1 = p[2]+p[3],   a2 = p[4]+p[5],   a3 = p[6]+p[7];
        float a4 = p[8]+p[9],   a5 = p[10]+p[11], a6 = p[12]+p[13], a7 = p[14]+p[15];
        ts = ((a0+a1)+(a2+a3)) + ((a4+a5)+(a6+a7));
        ts += __shfl_xor(ts, 32);
        l += ts;
      } else {
        float dm = fmaxf(tm, 0.f);
        negm -= dm;
        float sc = __builtin_amdgcn_exp2f(-dm);
#pragma unroll
        for (int r = 0; r < 16; ++r) p[r] = __builtin_amdgcn_exp2f(gm[r] - dm);
        float a0 = p[0]+p[1],   a1 = p[2]+p[3],   a2 = p[4]+p[5],   a3 = p[6]+p[7];
        float a4 = p[8]+p[9],   a5 = p[10]+p[11], a6 = p[12]+p[13], a7 = p[14]+p[15];
        ts = ((a0+a1)+(a2+a3)) + ((a4+a5)+(a6+a7));
        ts += __shfl_xor(ts, 32);
        l = __builtin_fmaf(l, sc, ts);
        float scr[16];
#pragma unroll
        for (int r = 0; r < 16; ++r)
          scr[r] = __shfl(sc, (r & 3) + 8 * (r >> 2) + 4 * hi);
#pragma unroll
        for (int n = 0; n < 4; ++n)
#pragma unroll
          for (int r = 0; r < 16; ++r) accO[n][r] *= scr[r];
      }

      // ---- P -> PV A-fragments in-register (T12; distinct operands only) --
      unsigned pk01 = pkrtz(p[0], p[1]),   pk23 = pkrtz(p[2], p[3]);
      unsigned pk45 = pkrtz(p[4], p[5]),   pk67 = pkrtz(p[6], p[7]);
      unsigned pk89 = pkrtz(p[8], p[9]),   pkAB = pkrtz(p[10], p[11]);
      unsigned pkCD = pkrtz(p[12], p[13]), pkEF = pkrtz(p[14], p[15]);
      u32x2 r0 = __builtin_amdgcn_permlane32_swap(pk01, pk45, false, false);
      u32x2 r1 = __builtin_amdgcn_permlane32_swap(pk23, pk67, false, false);
      u32x2 r2 = __builtin_amdgcn_permlane32_swap(pk89, pkCD, false, false);
      u32x2 r3 = __builtin_amdgcn_permlane32_swap(pkAB, pkEF, false, false);
      union { unsigned u[4]; f16x8 v; } A0c, A1c;
      A0c.u[0] = r0[0]; A0c.u[1] = r1[0]; A0c.u[2] = r0[1]; A0c.u[3] = r1[1];
      A1c.u[0] = r2[0]; A1c.u[1] = r3[0]; A1c.u[2] = r2[1]; A1c.u[3] = r3[1];

      // ---- O += P @ V ----
      __builtin_amdgcn_s_setprio(1);
#pragma unroll
      for (int n = 0; n < 4; ++n) {
        f16x8 vf0 = *(const f16x8*)(Vcur + (n * 32 + l5) * 64 +
                                    ((kb * 32 + hi * 8) ^ kvswz));
        accO[n] = __builtin_amdgcn_mfma_f32_32x32x16_f16(A0c.v, vf0, accO[n], 0, 0, 0);
        f16x8 vf1 = *(const f16x8*)(Vcur + (n * 32 + l5) * 64 +
                                    ((kb * 32 + 16 + hi * 8) ^ kvswz));
        accO[n] = __builtin_amdgcn_mfma_f32_32x32x16_f16(A1c.v, vf1, accO[n], 0, 0, 0);
      }
      __builtin_amdgcn_s_setprio(0);
    }

    __syncthreads();   // waves done with cur; prefetch into cur^1 landed
    cur ^= 1;
  }

  // ---- epilogue: O[q][d] / l[q]; q = (r&3)+8*(r>>2)+4*hi, d = n*32+l5 ----
  float linv = __builtin_amdgcn_rcpf(l);
  float lb[16];
#pragma unroll
  for (int r = 0; r < 16; ++r)
    lb[r] = __shfl(linv, (r & 3) + 8 * (r >> 2) + 4 * hi);
#pragma unroll
  for (int n = 0; n < 4; ++n)
#pragma unroll
    for (int r = 0; r < 16; ++r) {
      const int i = wq0 + (r & 3) + 8 * (r >> 2) + 4 * hi;
      out[((size_t)(b * L_ + i) * H_ + h) * D_ + n * 32 + l5] = accO[n][r] * lb[r];
    }
}

extern "C" void kernel_launch(void* const* d_in, const int* in_sizes, int n_in,
                              void* d_out, int out_size, void* d_ws, size_t ws_size,
                              hipStream_t stream) {
  const float* x  = (const float*)d_in[0];
  const float* W1 = (const float*)d_in[1];
  const float* b1 = (const float*)d_in[2];
  const float* W2 = (const float*)d_in[3];
  const float* b2 = (const float*)d_in[4];
  float* out = (float*)d_out;

  const size_t N = (size_t)BH_ * L_ * D_;
  _Float16* Qb = (_Float16*)d_ws;
  _Float16* Kb = Qb + N;
  _Float16* VT = Kb + N;

  _Float16* Wh1 = (_Float16*)d_out;          // scratch; attn overwrites out
  _Float16* Wh2 = Wh1 + D_ * D_;

  wcvt_kernel<<<64, 256, 0, stream>>>(W1, W2, Wh1, Wh2);
  proj_tr_kernel<<<(BH_ * L_) / 64, 256, 0, stream>>>(x, Wh1, b1, Wh2, b2, Qb, Kb, VT);
  attn_kernel<<<BH_ * (L_ / 256), 512, 0, stream>>>(Qb, Kb, VT, out);
}

// Round 12
// 364.288 us; speedup vs baseline: 1.4695x; 1.0160x over previous
//
#include <hip/hip_runtime.h>
#include <hip/hip_bf16.h>

#define B_ 4
#define H_ 16
#define L_ 2048
#define D_ 128
#define BH_ 64

typedef __attribute__((ext_vector_type(8))) _Float16 f16x8;
typedef __attribute__((ext_vector_type(4))) float f32x4;
typedef __attribute__((ext_vector_type(16))) float f32x16;
typedef __attribute__((ext_vector_type(2))) unsigned u32x2;

#define L2E 1.44269504088896f

// gm = L2E*gelu(v) + negm. erf via A&S 7.1.27 (|eps|<=5e-4): one rcp, no exp2.
__device__ __forceinline__ float gelu_m(float v, float negm) {
  float x  = __builtin_fabsf(v) * 0.70710678118f;
  float s  = __builtin_fmaf(x,
               __builtin_fmaf(x,
                 __builtin_fmaf(x,
                   __builtin_fmaf(x, 0.078108f, 0.000972f),
                 0.230389f),
               0.278393f),
             1.0f);
  float s2 = s * s;
  float s4 = s2 * s2;
  float erfa = 1.0f - __builtin_amdgcn_rcpf(s4);   // erf(|v|/sqrt2) in [0,1)
  float erfv = copysignf(erfa, v);
  float hv   = 0.72134752f * v;                    // 0.5*L2E*v
  return __builtin_fmaf(hv, erfv, hv + negm);      // hv*(1+erfv) + negm
}

__device__ __forceinline__ void gl2lds16(const void* g, void* l) {
  __builtin_amdgcn_global_load_lds(
      (const __attribute__((address_space(1))) void*)g,
      (__attribute__((address_space(3))) void*)l, 16, 0, 0);
}

__device__ __forceinline__ unsigned pkrtz(float a, float b) {
  auto t = __builtin_amdgcn_cvt_pkrtz(a, b);   // __fp16 ext_vector(2)
  return __builtin_bit_cast(unsigned, t);
}

// ---------------------------------------------------------------------------
// Kernel 0: one-time W1,W2 f32 -> f16 (scratch in d_out head; attn overwrites).
// ---------------------------------------------------------------------------
__global__ __launch_bounds__(256) void wcvt_kernel(
    const float* __restrict__ W1, const float* __restrict__ W2,
    _Float16* __restrict__ Wh1, _Float16* __restrict__ Wh2)
{
  int i = blockIdx.x * 256 + threadIdx.x;
  Wh1[i] = (_Float16)W1[i];
  Wh2[i] = (_Float16)W2[i];
}

// ---------------------------------------------------------------------------
// Kernel 1: q/k projections (f16 MFMA, f32 accum, +bias) and x -> V^T (f16).
// ---------------------------------------------------------------------------
__global__ __launch_bounds__(256) void proj_tr_kernel(
    const float* __restrict__ x,
    const _Float16* __restrict__ Wh1, const float* __restrict__ b1,
    const _Float16* __restrict__ Wh2, const float* __restrict__ b2,
    _Float16* __restrict__ Qb, _Float16* __restrict__ Kb,
    _Float16* __restrict__ VT)
{
  const int tid  = threadIdx.x;
  const int wave = tid >> 6;
  const int lane = tid & 63;
  const int lhi  = lane >> 4;
  const int llo  = lane & 15;
  const int r0   = blockIdx.x * 64;
  const int wr0  = r0 + wave * 16;

  f16x8 a[4];
#pragma unroll
  for (int ks = 0; ks < 4; ++ks) {
    const float* p = x + (size_t)(wr0 + llo) * D_ + lhi * 8 + ks * 32;
    f16x8 t;
#pragma unroll
    for (int e = 0; e < 8; ++e) t[e] = (_Float16)p[e];
    a[ks] = t;
  }

  f32x4 accq[8], acck[8];
#pragma unroll
  for (int n = 0; n < 8; ++n) {
    accq[n] = (f32x4){0.f, 0.f, 0.f, 0.f};
    acck[n] = (f32x4){0.f, 0.f, 0.f, 0.f};
  }

#pragma unroll
  for (int n = 0; n < 8; ++n) {
    const int e = n * 16 + llo;
#pragma unroll
    for (int ks = 0; ks < 4; ++ks) {
      f16x8 w1f = *(const f16x8*)(Wh1 + (size_t)e * D_ + lhi * 8 + ks * 32);
      f16x8 w2f = *(const f16x8*)(Wh2 + (size_t)e * D_ + lhi * 8 + ks * 32);
      accq[n] = __builtin_amdgcn_mfma_f32_16x16x32_f16(a[ks], w1f, accq[n], 0, 0, 0);
      acck[n] = __builtin_amdgcn_mfma_f32_16x16x32_f16(a[ks], w2f, acck[n], 0, 0, 0);
    }
  }

#pragma unroll
  for (int n = 0; n < 8; ++n) {
    const int e = n * 16 + llo;
    const float bias1 = b1[e];
    const float bias2 = b2[e];
#pragma unroll
    for (int r = 0; r < 4; ++r) {
      const size_t row = (size_t)wr0 + lhi * 4 + r;
      Qb[row * D_ + e] = (_Float16)(accq[n][r] + bias1);
      Kb[row * D_ + e] = (_Float16)(acck[n][r] + bias2);
    }
  }

  const int bh = r0 / L_;
  const int l0 = r0 % L_;
  const int d  = tid & 127;
  const int rh = tid >> 7;
  _Float16* dst = VT + (size_t)bh * D_ * L_ + (size_t)d * L_ + l0 + rh * 32;
#pragma unroll
  for (int j = 0; j < 4; ++j) {
    f16x8 t;
#pragma unroll
    for (int e = 0; e < 8; ++e)
      t[e] = (_Float16)x[(size_t)(r0 + rh * 32 + j * 8 + e) * D_ + d];
    *(f16x8*)(dst + j * 8) = t;
  }
}

// ---------------------------------------------------------------------------
// Kernel 2: fused gelu(QK^T)->softmax->@V flash attention, 32x32x16 MFMA.
// R11 + T15 software pipeline: BOTH kb subtiles' QK^T computed up front
// (two interleaved 8-deep MFMA chains, sA/sB live together -- spends the
// free VGPR headroom below the 256-reg occupancy step), then
// softmax(0) -> PV(0) -> softmax(1) -> PV(1): PV(0) MFMA overlaps
// softmax(1) VALU (independent), QK tail overlaps gelu(0).
// ---------------------------------------------------------------------------
__global__ __launch_bounds__(512) void attn_kernel(
    const _Float16* __restrict__ Qb, const _Float16* __restrict__ Kb,
    const _Float16* __restrict__ VT, float* __restrict__ out)
{
  __shared__ _Float16 Ks[2][64 * 128];   // 2 x 16KB
  __shared__ _Float16 Vs[2][128 * 64];   // 2 x 16KB

  const int tid  = threadIdx.x;
  const int wave = tid >> 6;      // 0..7
  const int lane = tid & 63;
  const int l5   = lane & 31;
  const int hi   = lane >> 5;

  // XCD-aware swizzle: 512 blocks, 8 XCDs -> 8 whole heads per XCD.
  const int bid = blockIdx.x;
  const int blk = (bid & 7) * 64 + (bid >> 3);
  const int bh  = blk >> 3;            // 8 q-blocks (256 rows) per head
  const int q0  = (blk & 7) * 256;
  const int b   = bh >> 4;
  const int h   = bh & 15;
  const int wq0 = q0 + wave * 32;

  const char* KheadB = (const char*)(Kb + (size_t)bh * L_ * D_);
  const char* VheadB = (const char*)(VT + (size_t)bh * D_ * L_);

  // ---- staging constants (16KB tile = 8 waves x 2 calls x 1KB each) ----
  int klds[2], ksrc[2], vlds[2], vsrc[2];
#pragma unroll
  for (int c = 0; c < 2; ++c) {
    const int wc = wave * 2 + c;
    klds[c] = wc * 1024;                               // wave-uniform LDS dest
    {
      const int l  = wc * 4 + (lane >> 4);             // K-tile row
      const int c0 = (lane & 15) * 8;                  // col halves
      ksrc[c] = l * 256 + 2 * (c0 ^ ((l & 7) << 3));   // pre-swizzled source
    }
    vlds[c] = wc * 1024;
    {
      const int d  = wc * 8 + (lane >> 3);             // V-tile row (d)
      const int c0 = (lane & 7) * 8;
      vsrc[c] = d * 4096 + 2 * (c0 ^ ((d & 7) << 3));
    }
  }
  const int kvswz = (l5 & 7) << 3;                     // read-side XOR (halves)

  // Q fragments (B-operand of swapped QK^T): j = l5 = q-row, k = s*16+hi*8+e
  f16x8 qf[8];
#pragma unroll
  for (int s = 0; s < 8; ++s)
    qf[s] = *(const f16x8*)(Qb + ((size_t)bh * L_ + wq0 + l5) * D_ + s * 16 + hi * 8);

  f32x16 accO[4];
#pragma unroll
  for (int n = 0; n < 4; ++n)
#pragma unroll
    for (int r = 0; r < 16; ++r) accO[n][r] = 0.f;
  float negm = 64.f;   // -m in exp2 units; m init -64
  float l = 0.f;

  // ---- prologue: stage tile 0 ----
#pragma unroll
  for (int c = 0; c < 2; ++c) {
    gl2lds16(KheadB + ksrc[c], (char*)&Ks[0][0] + klds[c]);
    gl2lds16(VheadB + vsrc[c], (char*)&Vs[0][0] + vlds[c]);
  }
  __syncthreads();

  int cur = 0;
  for (int t = 0; t < L_ / 64; ++t) {
    // ---- prefetch next K/V tile (in flight across the tile body) ----
    if (t + 1 < L_ / 64) {
      const char* kt_ = KheadB + (size_t)(t + 1) * 64 * 256;
      const char* vt_ = VheadB + (size_t)(t + 1) * 128;
#pragma unroll
      for (int c = 0; c < 2; ++c) {
        gl2lds16(kt_ + ksrc[c], (char*)&Ks[cur ^ 1][0] + klds[c]);
        gl2lds16(vt_ + vsrc[c], (char*)&Vs[cur ^ 1][0] + vlds[c]);
      }
    }
    const _Float16* Kcur = &Ks[cur][0];
    const _Float16* Vcur = &Vs[cur][0];

    // ---- S^T for BOTH kb subtiles: two interleaved 8-deep chains ----
    f32x16 sA, sB;
#pragma unroll
    for (int r = 0; r < 16; ++r) { sA[r] = 0.f; sB[r] = 0.f; }
    __builtin_amdgcn_s_setprio(1);
#pragma unroll
    for (int s = 0; s < 8; ++s) {
      f16x8 kfa = *(const f16x8*)(Kcur + l5 * 128 +
                                  ((s * 16 + hi * 8) ^ kvswz));
      sA = __builtin_amdgcn_mfma_f32_32x32x16_f16(kfa, qf[s], sA, 0, 0, 0);
      f16x8 kfb = *(const f16x8*)(Kcur + (32 + l5) * 128 +
                                  ((s * 16 + hi * 8) ^ kvswz));
      sB = __builtin_amdgcn_mfma_f32_32x32x16_f16(kfb, qf[s], sB, 0, 0, 0);
    }
    __builtin_amdgcn_s_setprio(0);

    // ---- softmax + PV per subtile; PV(0) MFMA overlaps softmax(1) VALU ----
    auto softmax_pv = [&](const f32x16& sT, int kb) {
      float gm[16];
#pragma unroll
      for (int r = 0; r < 16; ++r) gm[r] = gelu_m(sT[r], negm);

      float tm = fmaxf(fmaxf(gm[0], gm[1]), gm[2]);
      tm = fmaxf(fmaxf(tm, gm[3]),  gm[4]);
      tm = fmaxf(fmaxf(tm, gm[5]),  gm[6]);
      tm = fmaxf(fmaxf(tm, gm[7]),  gm[8]);
      tm = fmaxf(fmaxf(tm, gm[9]),  gm[10]);
      tm = fmaxf(fmaxf(tm, gm[11]), gm[12]);
      tm = fmaxf(fmaxf(tm, gm[13]), gm[14]);
      tm = fmaxf(tm, gm[15]);
      tm = fmaxf(tm, __shfl_xor(tm, 32));

      float p[16];
      float ts;
      if (__all(tm <= 11.5415603f)) {
#pragma unroll
        for (int r = 0; r < 16; ++r) p[r] = __builtin_amdgcn_exp2f(gm[r]);
        float a0 = p[0]+p[1],   a1 = p[2]+p[3],   a2 = p[4]+p[5],   a3 = p[6]+p[7];
        float a4 = p[8]+p[9],   a5 = p[10]+p[11], a6 = p[12]+p[13], a7 = p[14]+p[15];
        ts = ((a0+a1)+(a2+a3)) + ((a4+a5)+(a6+a7));
        ts += __shfl_xor(ts, 32);
        l += ts;
      } else {
        float dm = fmaxf(tm, 0.f);
        negm -= dm;
        float sc = __builtin_amdgcn_exp2f(-dm);
#pragma unroll
        for (int r = 0; r < 16; ++r) p[r] = __builtin_amdgcn_exp2f(gm[r] - dm);
        float a0 = p[0]+p[1],   a1 = p[2]+p[3],   a2 = p[4]+p[5],   a3 = p[6]+p[7];
        float a4 = p[8]+p[9],   a5 = p[10]+p[11], a6 = p[12]+p[13], a7 = p[14]+p[15];
        ts = ((a0+a1)+(a2+a3)) + ((a4+a5)+(a6+a7));
        ts += __shfl_xor(ts, 32);
        l = __builtin_fmaf(l, sc, ts);
        float scr[16];
#pragma unroll
        for (int r = 0; r < 16; ++r)
          scr[r] = __shfl(sc, (r & 3) + 8 * (r >> 2) + 4 * hi);
#pragma unroll
        for (int n = 0; n < 4; ++n)
#pragma unroll
          for (int r = 0; r < 16; ++r) accO[n][r] *= scr[r];
      }

      // P -> PV A-fragments in-register (T12; distinct operands only)
      unsigned pk01 = pkrtz(p[0], p[1]),   pk23 = pkrtz(p[2], p[3]);
      unsigned pk45 = pkrtz(p[4], p[5]),   pk67 = pkrtz(p[6], p[7]);
      unsigned pk89 = pkrtz(p[8], p[9]),   pkAB = pkrtz(p[10], p[11]);
      unsigned pkCD = pkrtz(p[12], p[13]), pkEF = pkrtz(p[14], p[15]);
      u32x2 r0 = __builtin_amdgcn_permlane32_swap(pk01, pk45, false, false);
      u32x2 r1 = __builtin_amdgcn_permlane32_swap(pk23, pk67, false, false);
      u32x2 r2 = __builtin_amdgcn_permlane32_swap(pk89, pkCD, false, false);
      u32x2 r3 = __builtin_amdgcn_permlane32_swap(pkAB, pkEF, false, false);
      union { unsigned u[4]; f16x8 v; } A0c, A1c;
      A0c.u[0] = r0[0]; A0c.u[1] = r1[0]; A0c.u[2] = r0[1]; A0c.u[3] = r1[1];
      A1c.u[0] = r2[0]; A1c.u[1] = r3[0]; A1c.u[2] = r2[1]; A1c.u[3] = r3[1];

      // O += P @ V
      __builtin_amdgcn_s_setprio(1);
#pragma unroll
      for (int n = 0; n < 4; ++n) {
        f16x8 vf0 = *(const f16x8*)(Vcur + (n * 32 + l5) * 64 +
                                    ((kb * 32 + hi * 8) ^ kvswz));
        accO[n] = __builtin_amdgcn_mfma_f32_32x32x16_f16(A0c.v, vf0, accO[n], 0, 0, 0);
        f16x8 vf1 = *(const f16x8*)(Vcur + (n * 32 + l5) * 64 +
                                    ((kb * 32 + 16 + hi * 8) ^ kvswz));
        accO[n] = __builtin_amdgcn_mfma_f32_32x32x16_f16(A1c.v, vf1, accO[n], 0, 0, 0);
      }
      __builtin_amdgcn_s_setprio(0);
    };

    softmax_pv(sA, 0);
    softmax_pv(sB, 1);

    __syncthreads();   // waves done with cur; prefetch into cur^1 landed
    cur ^= 1;
  }

  // ---- epilogue: O[q][d] / l[q]; q = (r&3)+8*(r>>2)+4*hi, d = n*32+l5 ----
  float linv = __builtin_amdgcn_rcpf(l);
  float lb[16];
#pragma unroll
  for (int r = 0; r < 16; ++r)
    lb[r] = __shfl(linv, (r & 3) + 8 * (r >> 2) + 4 * hi);
#pragma unroll
  for (int n = 0; n < 4; ++n)
#pragma unroll
    for (int r = 0; r < 16; ++r) {
      const int i = wq0 + (r & 3) + 8 * (r >> 2) + 4 * hi;
      out[((size_t)(b * L_ + i) * H_ + h) * D_ + n * 32 + l5] = accO[n][r] * lb[r];
    }
}

extern "C" void kernel_launch(void* const* d_in, const int* in_sizes, int n_in,
                              void* d_out, int out_size, void* d_ws, size_t ws_size,
                              hipStream_t stream) {
  const float* x  = (const float*)d_in[0];
  const float* W1 = (const float*)d_in[1];
  const float* b1 = (const float*)d_in[2];
  const float* W2 = (const float*)d_in[3];
  const float* b2 = (const float*)d_in[4];
  float* out = (float*)d_out;

  const size_t N = (size_t)BH_ * L_ * D_;
  _Float16* Qb = (_Float16*)d_ws;
  _Float16* Kb = Qb + N;
  _Float16* VT = Kb + N;

  _Float16* Wh1 = (_Float16*)d_out;          // scratch; attn overwrites out
  _Float16* Wh2 = Wh1 + D_ * D_;

  wcvt_kernel<<<64, 256, 0, stream>>>(W1, W2, Wh1, Wh2);
  proj_tr_kernel<<<(BH_ * L_) / 64, 256, 0, stream>>>(x, Wh1, b1, Wh2, b2, Qb, Kb, VT);
  attn_kernel<<<BH_ * (L_ / 256), 512, 0, stream>>>(Qb, Kb, VT, out);
}